// Round 1
// baseline (1153.526 us; speedup 1.0000x reference)
//
#include <hip/hip_runtime.h>
#include <hip/hip_bf16.h>

#define N_NODES 100000
#define N_EDGES 3200000
#define N_GRAPHS 256

// ---------------- workspace layout (bytes, 512-aligned) ----------------
#define OFF_CNT       0u            // int[N]     in-degree counts (zeroed)
#define OFF_FILL      400384u       // int[N]     scatter fill counters (zeroed)
#define OFF_SUMS      800768u       // float[256*64] pool sums (zeroed)
#define OFF_CNTF      866304u       // float[256] pool counts (zeroed)
#define ZERO_BYTES    867328u
#define OFF_ROWPTR    867328u       // int[N+1]
#define OFF_DINV      1267712u      // float[N]
#define OFF_BLKSUM    1668096u      // int[128]
#define OFF_BLKOFF    1668608u      // int[128]
#define OFF_COL       1669120u      // int[E]
#define OFF_XS1       14469120u     // float[N*8]
#define OFF_Z1        17669120u     // float[N*8]
#define OFF_BUFQ      20869120u     // float[N*64]  xs2, later z3
#define OFF_BUFR      46469120u     // float[N*64]  z2, later ys
#define OFF_BUFP      72069120u     // float[N*128] h2
// total ~123.3 MB

__global__ void zero_kernel(int* p, int n) {
    int i = blockIdx.x * 256 + threadIdx.x;
    if (i < n) p[i] = 0;
}

__global__ void count_kernel(const int* __restrict__ dst, int* __restrict__ cnt, int E) {
    int e = blockIdx.x * 256 + threadIdx.x;
    if (e < E) atomicAdd(&cnt[dst[e]], 1);
}

// ---- 3-phase exclusive scan of cnt[N] -> row_ptr[N+1]; also dinv = rsqrt(cnt+1)
__global__ void scanA_kernel(const int* __restrict__ cnt, int* __restrict__ row_ptr,
                             int* __restrict__ blockSum, float* __restrict__ dinv, int n) {
    __shared__ int s[1024];
    int t = threadIdx.x;
    int i = blockIdx.x * 1024 + t;
    int v = (i < n) ? cnt[i] : 0;
    s[t] = v;
    __syncthreads();
    for (int off = 1; off < 1024; off <<= 1) {
        int add = (t >= off) ? s[t - off] : 0;
        __syncthreads();
        s[t] += add;
        __syncthreads();
    }
    if (i < n) {
        row_ptr[i] = s[t] - v;                 // block-local exclusive
        dinv[i] = rsqrtf((float)(v + 1));
    }
    if (t == 1023) blockSum[blockIdx.x] = s[t];
}

__global__ void scanB_kernel(const int* __restrict__ blockSum, int* __restrict__ blockOff,
                             int* __restrict__ row_ptr, int nb, int n) {
    __shared__ int s[128];
    int t = threadIdx.x;
    int v = (t < nb) ? blockSum[t] : 0;
    s[t] = v;
    __syncthreads();
    for (int off = 1; off < 128; off <<= 1) {
        int add = (t >= off) ? s[t - off] : 0;
        __syncthreads();
        s[t] += add;
        __syncthreads();
    }
    blockOff[t] = s[t] - v;                    // exclusive
    if (t == 127) row_ptr[n] = s[127];         // total = E
}

__global__ void scanC_kernel(int* __restrict__ row_ptr, const int* __restrict__ blockOff, int n) {
    int i = blockIdx.x * 1024 + threadIdx.x;
    if (i < n) row_ptr[i] += blockOff[blockIdx.x];
}

__global__ void scatter_kernel(const int* __restrict__ src, const int* __restrict__ dst,
                               const int* __restrict__ row_ptr, int* __restrict__ fill,
                               int* __restrict__ col, int E) {
    int e = blockIdx.x * 256 + threadIdx.x;
    if (e < E) {
        int d = dst[e];
        int p = row_ptr[d] + atomicAdd(&fill[d], 1);
        col[p] = src[e];
    }
}

__global__ void scale_x8_kernel(const float* __restrict__ x, const float* __restrict__ dinv,
                                float* __restrict__ xs, int n8) {
    int i = blockIdx.x * 256 + threadIdx.x;
    if (i < n8) xs[i] = x[i] * dinv[i >> 3];
}

// z_i[f] = dinv_i * ( xs_i[f] + sum_{e in CSR row i} xs[col[e]][f] )
template <int D>
__global__ void agg_kernel(const float* __restrict__ xs, const int* __restrict__ row_ptr,
                           const int* __restrict__ col, const float* __restrict__ dinv,
                           float* __restrict__ z, int n) {
    constexpr int GROUPS = 256 / D;
    int node = blockIdx.x * GROUPS + threadIdx.x / D;
    int f = threadIdx.x % D;
    if (node >= n) return;
    int e0 = row_ptr[node], e1 = row_ptr[node + 1];
    float a0 = xs[node * D + f], a1 = 0.f, a2 = 0.f, a3 = 0.f;
    int e = e0;
    for (; e + 4 <= e1; e += 4) {
        int s0 = col[e], s1 = col[e + 1], s2 = col[e + 2], s3 = col[e + 3];
        a0 += xs[s0 * D + f];
        a1 += xs[s1 * D + f];
        a2 += xs[s2 * D + f];
        a3 += xs[s3 * D + f];
    }
    for (; e < e1; ++e) a0 += xs[col[e] * D + f];
    z[node * D + f] = dinv[node] * ((a0 + a1) + (a2 + a3));
}

// Y[row, :] = opt_scale(dinv[row]) * opt_relu( X[row,:] @ W + opt_bias )
template <int K, int M, bool BIAS, bool RELU, bool SCALE>
__global__ __launch_bounds__(256) void gemm_kernel(
        const float* __restrict__ X, const float* __restrict__ W,
        const float* __restrict__ b, const float* __restrict__ dinv,
        float* __restrict__ Y, int nrows) {
    constexpr int CG = M / 4;        // column groups of 4 (float4)
    constexpr int ROWS = 256 / CG;   // rows per tile
    __shared__ float Wl[K * M];
    __shared__ float Bl[M];
    __shared__ float Xl[ROWS * K];
    int tid = threadIdx.x;
    for (int i = tid; i < K * M; i += 256) Wl[i] = W[i];
    if (tid < M) {
        if constexpr (BIAS) Bl[tid] = b[tid];
        else Bl[tid] = 0.0f;
    }
    int ntiles = (nrows + ROWS - 1) / ROWS;
    for (int tile = blockIdx.x; tile < ntiles; tile += gridDim.x) {
        int row0 = tile * ROWS;
        __syncthreads();
        for (int i = tid; i < ROWS * K; i += 256) {
            int gi = row0 * K + i;
            Xl[i] = (gi < nrows * K) ? X[gi] : 0.0f;
        }
        __syncthreads();
        int r = tid / CG, cg = tid % CG;
        int row = row0 + r;
        if (row < nrows) {
            float4 acc;
            acc.x = Bl[cg * 4 + 0];
            acc.y = Bl[cg * 4 + 1];
            acc.z = Bl[cg * 4 + 2];
            acc.w = Bl[cg * 4 + 3];
#pragma unroll
            for (int k = 0; k < K; ++k) {
                float xv = Xl[r * K + k];
                const float4 w = *reinterpret_cast<const float4*>(&Wl[k * M + cg * 4]);
                acc.x += xv * w.x;
                acc.y += xv * w.y;
                acc.z += xv * w.z;
                acc.w += xv * w.w;
            }
            if constexpr (RELU) {
                acc.x = fmaxf(acc.x, 0.f); acc.y = fmaxf(acc.y, 0.f);
                acc.z = fmaxf(acc.z, 0.f); acc.w = fmaxf(acc.w, 0.f);
            }
            if constexpr (SCALE) {
                float d = dinv[row];
                acc.x *= d; acc.y *= d; acc.z *= d; acc.w *= d;
            }
            *reinterpret_cast<float4*>(&Y[row * M + cg * 4]) = acc;
        }
    }
}

// h3 = relu(z3 + b3); pool sums/counts per graph
__global__ void pool_kernel(const float* __restrict__ z3, const float* __restrict__ b3,
                            const int* __restrict__ batch, float* __restrict__ sums,
                            float* __restrict__ cntf, int n) {
    int i = blockIdx.x * 256 + threadIdx.x;
    if (i >= n * 64) return;
    int node = i >> 6, f = i & 63;
    int g = batch[node];
    float v = fmaxf(z3[i] + b3[f], 0.0f);
    atomicAdd(&sums[g * 64 + f], v);
    if (f == 0) atomicAdd(&cntf[g], 1.0f);
}

// per-graph: g = sums/max(cnt,1); hid = relu(g@Wl1+bl1); out = hid@Wl2+bl2
__global__ void mlp_kernel(const float* __restrict__ sums, const float* __restrict__ cntf,
                           const float* __restrict__ Wl1, const float* __restrict__ bl1,
                           const float* __restrict__ Wl2, const float* __restrict__ bl2,
                           float* __restrict__ out) {
    __shared__ float gv[64];
    __shared__ float hid[32];
    int g = blockIdx.x, t = threadIdx.x;
    float denom = fmaxf(cntf[g], 1.0f);
    gv[t] = sums[g * 64 + t] / denom;
    __syncthreads();
    if (t < 32) {
        float a = bl1[t];
#pragma unroll
        for (int k = 0; k < 64; ++k) a += gv[k] * Wl1[k * 32 + t];
        hid[t] = fmaxf(a, 0.0f);
    }
    __syncthreads();
    if (t == 0) {
        float o = bl2[0];
#pragma unroll
        for (int k = 0; k < 32; ++k) o += hid[k] * Wl2[k];
        out[g] = o;
    }
}

extern "C" void kernel_launch(void* const* d_in, const int* in_sizes, int n_in,
                              void* d_out, int out_size, void* d_ws, size_t ws_size,
                              hipStream_t stream) {
    const float* x   = (const float*)d_in[0];
    const int* ei    = (const int*)d_in[1];
    const int* batch = (const int*)d_in[2];
    const float* W1  = (const float*)d_in[3];
    const float* b1  = (const float*)d_in[4];
    const float* W2  = (const float*)d_in[5];
    const float* b2  = (const float*)d_in[6];
    const float* W3  = (const float*)d_in[7];
    const float* b3  = (const float*)d_in[8];
    const float* Wl1 = (const float*)d_in[9];
    const float* bl1 = (const float*)d_in[10];
    const float* Wl2 = (const float*)d_in[11];
    const float* bl2 = (const float*)d_in[12];
    float* out = (float*)d_out;

    const int N = N_NODES;
    const int E = in_sizes[1] / 2;   // 3.2M
    const int* src = ei;
    const int* dst = ei + E;

    char* ws = (char*)d_ws;
    int*   cnt     = (int*)(ws + OFF_CNT);
    int*   fill    = (int*)(ws + OFF_FILL);
    float* sums    = (float*)(ws + OFF_SUMS);
    float* cntf    = (float*)(ws + OFF_CNTF);
    int*   row_ptr = (int*)(ws + OFF_ROWPTR);
    float* dinv    = (float*)(ws + OFF_DINV);
    int*   blkSum  = (int*)(ws + OFF_BLKSUM);
    int*   blkOff  = (int*)(ws + OFF_BLKOFF);
    int*   col     = (int*)(ws + OFF_COL);
    float* xs1     = (float*)(ws + OFF_XS1);
    float* z1      = (float*)(ws + OFF_Z1);
    float* bufQ    = (float*)(ws + OFF_BUFQ);   // xs2, later z3
    float* bufR    = (float*)(ws + OFF_BUFR);   // z2, later ys
    float* bufP    = (float*)(ws + OFF_BUFP);   // h2

    // zero counters/accumulators
    {
        int nz = ZERO_BYTES / 4;
        zero_kernel<<<(nz + 255) / 256, 256, 0, stream>>>((int*)ws, nz);
    }

    // CSR build
    count_kernel<<<(E + 255) / 256, 256, 0, stream>>>(dst, cnt, E);
    int nb = (N + 1023) / 1024;   // 98
    scanA_kernel<<<nb, 1024, 0, stream>>>(cnt, row_ptr, blkSum, dinv, N);
    scanB_kernel<<<1, 128, 0, stream>>>(blkSum, blkOff, row_ptr, nb, N);
    scanC_kernel<<<nb, 1024, 0, stream>>>(row_ptr, blkOff, N);
    scatter_kernel<<<(E + 255) / 256, 256, 0, stream>>>(src, dst, row_ptr, fill, col, E);

    // Layer 1: xs1 = dinv*x ; z1 = agg(xs1) ; xs2 = dinv*relu(z1@W1+b1)
    scale_x8_kernel<<<(N * 8 + 255) / 256, 256, 0, stream>>>(x, dinv, xs1, N * 8);
    agg_kernel<8><<<(N + 31) / 32, 256, 0, stream>>>(xs1, row_ptr, col, dinv, z1, N);
    gemm_kernel<8, 64, true, true, true><<<2560, 256, 0, stream>>>(z1, W1, b1, dinv, bufQ, N);

    // Layer 2: z2 = agg(xs2) ; h2 = relu(z2@W2+b2)
    agg_kernel<64><<<(N + 3) / 4, 256, 0, stream>>>(bufQ, row_ptr, col, dinv, bufR, N);
    gemm_kernel<64, 128, true, true, false><<<2560, 256, 0, stream>>>(bufR, W2, b2, nullptr, bufP, N);

    // Layer 3: ys = dinv*(h2@W3) ; z3 = agg(ys) ; (relu(z3+b3) fused into pool)
    gemm_kernel<128, 64, false, false, true><<<2560, 256, 0, stream>>>(bufP, W3, nullptr, dinv, bufR, N);
    agg_kernel<64><<<(N + 3) / 4, 256, 0, stream>>>(bufR, row_ptr, col, dinv, bufQ, N);

    // Pool + MLP head
    pool_kernel<<<(N * 64 + 255) / 256, 256, 0, stream>>>(bufQ, b3, batch, sums, cntf, N);
    mlp_kernel<<<N_GRAPHS, 64, 0, stream>>>(sums, cntf, Wl1, bl1, Wl2, bl2, out);
}

// Round 2
// 843.531 us; speedup vs baseline: 1.3675x; 1.3675x over previous
//
#include <hip/hip_runtime.h>
#include <hip/hip_bf16.h>

#define N_NODES 100000
#define N_EDGES 3200000
#define N_GRAPHS 256

// ---------------- workspace layout (bytes, 512-aligned) ----------------
#define OFF_CNT       0u            // int[N]     in-degree counts (zeroed)
#define OFF_FILL      400384u       // int[N]     scatter fill counters (zeroed)
#define OFF_SUMS      800768u       // float[256*64] pool sums (zeroed)
#define OFF_CNTF      866304u       // float[256] pool counts (zeroed)
#define ZERO_BYTES    867328u
#define OFF_ROWPTR    867328u       // int[N+1]
#define OFF_DINV      1267712u      // float[N]
#define OFF_BLKSUM    1668096u      // int[128]
#define OFF_BLKOFF    1668608u      // int[128]
#define OFF_COL       1669120u      // int[E]
#define OFF_XS1       14469120u     // float[N*8]
#define OFF_Z1        17669120u     // float[N*8]
#define OFF_BUFQ      20869120u     // float[N*64]  xs2, later z3
#define OFF_BUFR      46469120u     // float[N*64]  z2, later ys
#define OFF_BUFP      72069120u     // float[N*128] h2
// total ~123.3 MB

__global__ void zero_kernel(int* p, int n) {
    int i = blockIdx.x * 256 + threadIdx.x;
    if (i < n) p[i] = 0;
}

__global__ void count_kernel(const int* __restrict__ dst, int* __restrict__ cnt, int E) {
    int e = blockIdx.x * 256 + threadIdx.x;
    if (e < E) atomicAdd(&cnt[dst[e]], 1);
}

// ---- 3-phase exclusive scan of cnt[N] -> row_ptr[N+1]; also dinv = rsqrt(cnt+1)
__global__ void scanA_kernel(const int* __restrict__ cnt, int* __restrict__ row_ptr,
                             int* __restrict__ blockSum, float* __restrict__ dinv, int n) {
    __shared__ int s[1024];
    int t = threadIdx.x;
    int i = blockIdx.x * 1024 + t;
    int v = (i < n) ? cnt[i] : 0;
    s[t] = v;
    __syncthreads();
    for (int off = 1; off < 1024; off <<= 1) {
        int add = (t >= off) ? s[t - off] : 0;
        __syncthreads();
        s[t] += add;
        __syncthreads();
    }
    if (i < n) {
        row_ptr[i] = s[t] - v;                 // block-local exclusive
        dinv[i] = rsqrtf((float)(v + 1));
    }
    if (t == 1023) blockSum[blockIdx.x] = s[t];
}

__global__ void scanB_kernel(const int* __restrict__ blockSum, int* __restrict__ blockOff,
                             int* __restrict__ row_ptr, int nb, int n) {
    __shared__ int s[128];
    int t = threadIdx.x;
    int v = (t < nb) ? blockSum[t] : 0;
    s[t] = v;
    __syncthreads();
    for (int off = 1; off < 128; off <<= 1) {
        int add = (t >= off) ? s[t - off] : 0;
        __syncthreads();
        s[t] += add;
        __syncthreads();
    }
    blockOff[t] = s[t] - v;                    // exclusive
    if (t == 127) row_ptr[n] = s[127];         // total = E
}

__global__ void scanC_kernel(int* __restrict__ row_ptr, const int* __restrict__ blockOff, int n) {
    int i = blockIdx.x * 1024 + threadIdx.x;
    if (i < n) row_ptr[i] += blockOff[blockIdx.x];
}

__global__ void scatter_kernel(const int* __restrict__ src, const int* __restrict__ dst,
                               const int* __restrict__ row_ptr, int* __restrict__ fill,
                               int* __restrict__ col, int E) {
    int e = blockIdx.x * 256 + threadIdx.x;
    if (e < E) {
        int d = dst[e];
        int p = row_ptr[d] + atomicAdd(&fill[d], 1);
        col[p] = src[e];
    }
}

__global__ void scale_x8_kernel(const float* __restrict__ x, const float* __restrict__ dinv,
                                float* __restrict__ xs, int n8) {
    int i = blockIdx.x * 256 + threadIdx.x;
    if (i < n8) xs[i] = x[i] * dinv[i >> 3];
}

// z_i[f] = dinv_i * ( xs_i[f] + sum_{e in CSR row i} xs[col[e]][f] )
template <int D>
__global__ void agg_kernel(const float* __restrict__ xs, const int* __restrict__ row_ptr,
                           const int* __restrict__ col, const float* __restrict__ dinv,
                           float* __restrict__ z, int n) {
    constexpr int GROUPS = 256 / D;
    int node = blockIdx.x * GROUPS + threadIdx.x / D;
    int f = threadIdx.x % D;
    if (node >= n) return;
    int e0 = row_ptr[node], e1 = row_ptr[node + 1];
    float a0 = xs[node * D + f], a1 = 0.f, a2 = 0.f, a3 = 0.f;
    int e = e0;
    for (; e + 4 <= e1; e += 4) {
        int s0 = col[e], s1 = col[e + 1], s2 = col[e + 2], s3 = col[e + 3];
        a0 += xs[s0 * D + f];
        a1 += xs[s1 * D + f];
        a2 += xs[s2 * D + f];
        a3 += xs[s3 * D + f];
    }
    for (; e < e1; ++e) a0 += xs[col[e] * D + f];
    z[node * D + f] = dinv[node] * ((a0 + a1) + (a2 + a3));
}

// Y[row, :] = opt_scale(dinv[row]) * opt_relu( X[row,:] @ W + opt_bias )
template <int K, int M, bool BIAS, bool RELU, bool SCALE>
__global__ __launch_bounds__(256) void gemm_kernel(
        const float* __restrict__ X, const float* __restrict__ W,
        const float* __restrict__ b, const float* __restrict__ dinv,
        float* __restrict__ Y, int nrows) {
    constexpr int CG = M / 4;        // column groups of 4 (float4)
    constexpr int ROWS = 256 / CG;   // rows per tile
    __shared__ float Wl[K * M];
    __shared__ float Bl[M];
    __shared__ float Xl[ROWS * K];
    int tid = threadIdx.x;
    for (int i = tid; i < K * M; i += 256) Wl[i] = W[i];
    if (tid < M) {
        if constexpr (BIAS) Bl[tid] = b[tid];
        else Bl[tid] = 0.0f;
    }
    int ntiles = (nrows + ROWS - 1) / ROWS;
    for (int tile = blockIdx.x; tile < ntiles; tile += gridDim.x) {
        int row0 = tile * ROWS;
        __syncthreads();
        for (int i = tid; i < ROWS * K; i += 256) {
            int gi = row0 * K + i;
            Xl[i] = (gi < nrows * K) ? X[gi] : 0.0f;
        }
        __syncthreads();
        int r = tid / CG, cg = tid % CG;
        int row = row0 + r;
        if (row < nrows) {
            float4 acc;
            acc.x = Bl[cg * 4 + 0];
            acc.y = Bl[cg * 4 + 1];
            acc.z = Bl[cg * 4 + 2];
            acc.w = Bl[cg * 4 + 3];
#pragma unroll
            for (int k = 0; k < K; ++k) {
                float xv = Xl[r * K + k];
                const float4 w = *reinterpret_cast<const float4*>(&Wl[k * M + cg * 4]);
                acc.x += xv * w.x;
                acc.y += xv * w.y;
                acc.z += xv * w.z;
                acc.w += xv * w.w;
            }
            if constexpr (RELU) {
                acc.x = fmaxf(acc.x, 0.f); acc.y = fmaxf(acc.y, 0.f);
                acc.z = fmaxf(acc.z, 0.f); acc.w = fmaxf(acc.w, 0.f);
            }
            if constexpr (SCALE) {
                float d = dinv[row];
                acc.x *= d; acc.y *= d; acc.z *= d; acc.w *= d;
            }
            *reinterpret_cast<float4*>(&Y[row * M + cg * 4]) = acc;
        }
    }
}

// h3 = relu(z3 + b3); pool sums/counts per graph.
// batch is SORTED -> graph id is monotone over nodes. Each wave (64 lanes =
// 64 features) walks a strided slice of the block's node range, accumulating
// the current graph's partial sum in a register and flushing once per
// graph-run. Atomics: ~90K total instead of 6.4M (was 400 us of pure
// atomic serialization on 16K addresses).
#define POOL_NPB 1024   // nodes per block
__global__ __launch_bounds__(256) void pool_kernel(
        const float* __restrict__ z3, const float* __restrict__ b3,
        const int* __restrict__ batch, float* __restrict__ sums,
        float* __restrict__ cntf, int n) {
    int wave = threadIdx.x >> 6;
    int lane = threadIdx.x & 63;   // feature index
    int node0 = blockIdx.x * POOL_NPB;
    int nodeEnd = node0 + POOL_NPB;
    if (nodeEnd > n) nodeEnd = n;
    float bias = b3[lane];
    float acc = 0.0f, cnt = 0.0f;
    int curg = -1;
    for (int node = node0 + wave; node < nodeEnd; node += 4) {
        int g = batch[node];               // wave-uniform (lane = feature)
        if (g != curg) {                   // wave-uniform branch
            if (curg >= 0) {
                atomicAdd(&sums[curg * 64 + lane], acc);
                if (lane == 0) atomicAdd(&cntf[curg], cnt);
            }
            curg = g; acc = 0.0f; cnt = 0.0f;
        }
        acc += fmaxf(z3[node * 64 + lane] + bias, 0.0f);
        cnt += 1.0f;
    }
    if (curg >= 0) {
        atomicAdd(&sums[curg * 64 + lane], acc);
        if (lane == 0) atomicAdd(&cntf[curg], cnt);
    }
}

// per-graph: g = sums/max(cnt,1); hid = relu(g@Wl1+bl1); out = hid@Wl2+bl2
__global__ void mlp_kernel(const float* __restrict__ sums, const float* __restrict__ cntf,
                           const float* __restrict__ Wl1, const float* __restrict__ bl1,
                           const float* __restrict__ Wl2, const float* __restrict__ bl2,
                           float* __restrict__ out) {
    __shared__ float gv[64];
    __shared__ float hid[32];
    int g = blockIdx.x, t = threadIdx.x;
    float denom = fmaxf(cntf[g], 1.0f);
    gv[t] = sums[g * 64 + t] / denom;
    __syncthreads();
    if (t < 32) {
        float a = bl1[t];
#pragma unroll
        for (int k = 0; k < 64; ++k) a += gv[k] * Wl1[k * 32 + t];
        hid[t] = fmaxf(a, 0.0f);
    }
    __syncthreads();
    if (t == 0) {
        float o = bl2[0];
#pragma unroll
        for (int k = 0; k < 32; ++k) o += hid[k] * Wl2[k];
        out[g] = o;
    }
}

extern "C" void kernel_launch(void* const* d_in, const int* in_sizes, int n_in,
                              void* d_out, int out_size, void* d_ws, size_t ws_size,
                              hipStream_t stream) {
    const float* x   = (const float*)d_in[0];
    const int* ei    = (const int*)d_in[1];
    const int* batch = (const int*)d_in[2];
    const float* W1  = (const float*)d_in[3];
    const float* b1  = (const float*)d_in[4];
    const float* W2  = (const float*)d_in[5];
    const float* b2  = (const float*)d_in[6];
    const float* W3  = (const float*)d_in[7];
    const float* b3  = (const float*)d_in[8];
    const float* Wl1 = (const float*)d_in[9];
    const float* bl1 = (const float*)d_in[10];
    const float* Wl2 = (const float*)d_in[11];
    const float* bl2 = (const float*)d_in[12];
    float* out = (float*)d_out;

    const int N = N_NODES;
    const int E = in_sizes[1] / 2;   // 3.2M
    const int* src = ei;
    const int* dst = ei + E;

    char* ws = (char*)d_ws;
    int*   cnt     = (int*)(ws + OFF_CNT);
    int*   fill    = (int*)(ws + OFF_FILL);
    float* sums    = (float*)(ws + OFF_SUMS);
    float* cntf    = (float*)(ws + OFF_CNTF);
    int*   row_ptr = (int*)(ws + OFF_ROWPTR);
    float* dinv    = (float*)(ws + OFF_DINV);
    int*   blkSum  = (int*)(ws + OFF_BLKSUM);
    int*   blkOff  = (int*)(ws + OFF_BLKOFF);
    int*   col     = (int*)(ws + OFF_COL);
    float* xs1     = (float*)(ws + OFF_XS1);
    float* z1      = (float*)(ws + OFF_Z1);
    float* bufQ    = (float*)(ws + OFF_BUFQ);   // xs2, later z3
    float* bufR    = (float*)(ws + OFF_BUFR);   // z2, later ys
    float* bufP    = (float*)(ws + OFF_BUFP);   // h2

    // zero counters/accumulators
    {
        int nz = ZERO_BYTES / 4;
        zero_kernel<<<(nz + 255) / 256, 256, 0, stream>>>((int*)ws, nz);
    }

    // CSR build
    count_kernel<<<(E + 255) / 256, 256, 0, stream>>>(dst, cnt, E);
    int nb = (N + 1023) / 1024;   // 98
    scanA_kernel<<<nb, 1024, 0, stream>>>(cnt, row_ptr, blkSum, dinv, N);
    scanB_kernel<<<1, 128, 0, stream>>>(blkSum, blkOff, row_ptr, nb, N);
    scanC_kernel<<<nb, 1024, 0, stream>>>(row_ptr, blkOff, N);
    scatter_kernel<<<(E + 255) / 256, 256, 0, stream>>>(src, dst, row_ptr, fill, col, E);

    // Layer 1: xs1 = dinv*x ; z1 = agg(xs1) ; xs2 = dinv*relu(z1@W1+b1)
    scale_x8_kernel<<<(N * 8 + 255) / 256, 256, 0, stream>>>(x, dinv, xs1, N * 8);
    agg_kernel<8><<<(N + 31) / 32, 256, 0, stream>>>(xs1, row_ptr, col, dinv, z1, N);
    gemm_kernel<8, 64, true, true, true><<<2560, 256, 0, stream>>>(z1, W1, b1, dinv, bufQ, N);

    // Layer 2: z2 = agg(xs2) ; h2 = relu(z2@W2+b2)
    agg_kernel<64><<<(N + 3) / 4, 256, 0, stream>>>(bufQ, row_ptr, col, dinv, bufR, N);
    gemm_kernel<64, 128, true, true, false><<<2560, 256, 0, stream>>>(bufR, W2, b2, nullptr, bufP, N);

    // Layer 3: ys = dinv*(h2@W3) ; z3 = agg(ys) ; (relu(z3+b3) fused into pool)
    gemm_kernel<128, 64, false, false, true><<<2560, 256, 0, stream>>>(bufP, W3, nullptr, dinv, bufR, N);
    agg_kernel<64><<<(N + 3) / 4, 256, 0, stream>>>(bufR, row_ptr, col, dinv, bufQ, N);

    // Pool + MLP head
    pool_kernel<<<(N + POOL_NPB - 1) / POOL_NPB, 256, 0, stream>>>(bufQ, b3, batch, sums, cntf, N);
    mlp_kernel<<<N_GRAPHS, 64, 0, stream>>>(sums, cntf, Wl1, bl1, Wl2, bl2, out);
}

// Round 3
// 819.355 us; speedup vs baseline: 1.4078x; 1.0295x over previous
//
#include <hip/hip_runtime.h>
#include <hip/hip_bf16.h>

#define N_NODES 100000
#define N_EDGES 3200000
#define N_GRAPHS 256

// ---------------- workspace layout (bytes, 512-aligned) ----------------
#define OFF_CNT       0u            // int[N]     in-degree counts (zeroed)
#define OFF_FILL      400384u       // int[N]     scatter fill counters (zeroed)
#define OFF_SUMS      800768u       // float[256*64] pool sums (zeroed)
#define OFF_CNTF      866304u       // float[256] pool counts (zeroed)
#define ZERO_BYTES    867328u
#define OFF_ROWPTR    867328u       // int[N+1]
#define OFF_DINV      1267712u      // float[N]
#define OFF_BLKSUM    1668096u      // int[128]
#define OFF_BLKOFF    1668608u      // int[128]
#define OFF_COL       1669120u      // int[E]
#define OFF_XS1       14469120u     // float[N*8]
#define OFF_Z1        17669120u     // float[N*8]
#define OFF_BUFQ      20869120u     // float[N*64]  xs2, later z3
#define OFF_BUFR      46469120u     // float[N*64]  z2, later ys
#define OFF_BUFP      72069120u     // float[N*128] h2
// total ~123.3 MB

__global__ void zero_kernel(int* p, int n) {
    int i = blockIdx.x * 256 + threadIdx.x;
    if (i < n) p[i] = 0;
}

__global__ void count_kernel(const int* __restrict__ dst, int* __restrict__ cnt, int E) {
    int e = blockIdx.x * 256 + threadIdx.x;
    if (e < E) atomicAdd(&cnt[dst[e]], 1);
}

// ---- 3-phase exclusive scan of cnt[N] -> row_ptr[N+1]; also dinv = rsqrt(cnt+1)
__global__ void scanA_kernel(const int* __restrict__ cnt, int* __restrict__ row_ptr,
                             int* __restrict__ blockSum, float* __restrict__ dinv, int n) {
    __shared__ int s[1024];
    int t = threadIdx.x;
    int i = blockIdx.x * 1024 + t;
    int v = (i < n) ? cnt[i] : 0;
    s[t] = v;
    __syncthreads();
    for (int off = 1; off < 1024; off <<= 1) {
        int add = (t >= off) ? s[t - off] : 0;
        __syncthreads();
        s[t] += add;
        __syncthreads();
    }
    if (i < n) {
        row_ptr[i] = s[t] - v;                 // block-local exclusive
        dinv[i] = rsqrtf((float)(v + 1));
    }
    if (t == 1023) blockSum[blockIdx.x] = s[t];
}

__global__ void scanB_kernel(const int* __restrict__ blockSum, int* __restrict__ blockOff,
                             int* __restrict__ row_ptr, int nb, int n) {
    __shared__ int s[128];
    int t = threadIdx.x;
    int v = (t < nb) ? blockSum[t] : 0;
    s[t] = v;
    __syncthreads();
    for (int off = 1; off < 128; off <<= 1) {
        int add = (t >= off) ? s[t - off] : 0;
        __syncthreads();
        s[t] += add;
        __syncthreads();
    }
    blockOff[t] = s[t] - v;                    // exclusive
    if (t == 127) row_ptr[n] = s[127];         // total = E
}

__global__ void scanC_kernel(int* __restrict__ row_ptr, const int* __restrict__ blockOff, int n) {
    int i = blockIdx.x * 1024 + threadIdx.x;
    if (i < n) row_ptr[i] += blockOff[blockIdx.x];
}

// XCD-sliced scatter: slice = blockIdx&7 round-robins across the 8 XCDs;
// each slice owns a contiguous 12.5K-node dst range whose col region
// (~1.6 MB) fits in one XCD's 4 MiB L2, so scatter lines fill completely
// before eviction (was: 16x write amplification, 197 MB HBM writes).
// dst is re-read 8x but stays L3-resident. Correct under ANY block->XCD
// mapping; the slicing is purely a locality heuristic.
#define SCAT_EPB (256 * 16)   // edges per block per slice
__global__ __launch_bounds__(256) void scatter_kernel(
        const int* __restrict__ src, const int* __restrict__ dst,
        const int* __restrict__ row_ptr, int* __restrict__ fill,
        int* __restrict__ col, int E) {
    int slice = blockIdx.x & 7;
    int chunk = blockIdx.x >> 3;
    int lo = slice * (N_NODES / 8);
    int hi = lo + (N_NODES / 8);          // N_NODES % 8 == 0
    int base = chunk * SCAT_EPB + threadIdx.x;
#pragma unroll
    for (int k = 0; k < 16; ++k) {
        int e = base + k * 256;
        if (e < E) {
            int d = dst[e];
            if (d >= lo && d < hi) {
                int p = row_ptr[d] + atomicAdd(&fill[d], 1);
                col[p] = src[e];
            }
        }
    }
}

__global__ void scale_x8_kernel(const float* __restrict__ x, const float* __restrict__ dinv,
                                float* __restrict__ xs, int n8) {
    int i = blockIdx.x * 256 + threadIdx.x;
    if (i < n8) xs[i] = x[i] * dinv[i >> 3];
}

// z_i[f] = dinv_i * ( xs_i[f] + sum_{e in CSR row i} xs[col[e]][f] )
template <int D>
__global__ void agg_kernel(const float* __restrict__ xs, const int* __restrict__ row_ptr,
                           const int* __restrict__ col, const float* __restrict__ dinv,
                           float* __restrict__ z, int n) {
    constexpr int GROUPS = 256 / D;
    int node = blockIdx.x * GROUPS + threadIdx.x / D;
    int f = threadIdx.x % D;
    if (node >= n) return;
    int e0 = row_ptr[node], e1 = row_ptr[node + 1];
    float a0 = xs[node * D + f], a1 = 0.f, a2 = 0.f, a3 = 0.f;
    int e = e0;
    for (; e + 4 <= e1; e += 4) {
        int s0 = col[e], s1 = col[e + 1], s2 = col[e + 2], s3 = col[e + 3];
        a0 += xs[s0 * D + f];
        a1 += xs[s1 * D + f];
        a2 += xs[s2 * D + f];
        a3 += xs[s3 * D + f];
    }
    for (; e < e1; ++e) a0 += xs[col[e] * D + f];
    z[node * D + f] = dinv[node] * ((a0 + a1) + (a2 + a3));
}

// Y[row, :] = opt_scale(dinv[row]) * opt_relu( X[row,:] @ W + opt_bias )
template <int K, int M, bool BIAS, bool RELU, bool SCALE>
__global__ __launch_bounds__(256) void gemm_kernel(
        const float* __restrict__ X, const float* __restrict__ W,
        const float* __restrict__ b, const float* __restrict__ dinv,
        float* __restrict__ Y, int nrows) {
    constexpr int CG = M / 4;        // column groups of 4 (float4)
    constexpr int ROWS = 256 / CG;   // rows per tile
    __shared__ float Wl[K * M];
    __shared__ float Bl[M];
    __shared__ float Xl[ROWS * K];
    int tid = threadIdx.x;
    for (int i = tid; i < K * M; i += 256) Wl[i] = W[i];
    if (tid < M) {
        if constexpr (BIAS) Bl[tid] = b[tid];
        else Bl[tid] = 0.0f;
    }
    int ntiles = (nrows + ROWS - 1) / ROWS;
    for (int tile = blockIdx.x; tile < ntiles; tile += gridDim.x) {
        int row0 = tile * ROWS;
        __syncthreads();
        for (int i = tid; i < ROWS * K; i += 256) {
            int gi = row0 * K + i;
            Xl[i] = (gi < nrows * K) ? X[gi] : 0.0f;
        }
        __syncthreads();
        int r = tid / CG, cg = tid % CG;
        int row = row0 + r;
        if (row < nrows) {
            float4 acc;
            acc.x = Bl[cg * 4 + 0];
            acc.y = Bl[cg * 4 + 1];
            acc.z = Bl[cg * 4 + 2];
            acc.w = Bl[cg * 4 + 3];
#pragma unroll
            for (int k = 0; k < K; ++k) {
                float xv = Xl[r * K + k];
                const float4 w = *reinterpret_cast<const float4*>(&Wl[k * M + cg * 4]);
                acc.x += xv * w.x;
                acc.y += xv * w.y;
                acc.z += xv * w.z;
                acc.w += xv * w.w;
            }
            if constexpr (RELU) {
                acc.x = fmaxf(acc.x, 0.f); acc.y = fmaxf(acc.y, 0.f);
                acc.z = fmaxf(acc.z, 0.f); acc.w = fmaxf(acc.w, 0.f);
            }
            if constexpr (SCALE) {
                float d = dinv[row];
                acc.x *= d; acc.y *= d; acc.z *= d; acc.w *= d;
            }
            *reinterpret_cast<float4*>(&Y[row * M + cg * 4]) = acc;
        }
    }
}

// h3 = relu(z3 + b3); pool sums/counts per graph.
// batch is SORTED -> graph id is monotone over nodes; register-accumulate
// per graph-run, flush once per run (atomics ~90K instead of 6.4M).
#define POOL_NPB 1024   // nodes per block
__global__ __launch_bounds__(256) void pool_kernel(
        const float* __restrict__ z3, const float* __restrict__ b3,
        const int* __restrict__ batch, float* __restrict__ sums,
        float* __restrict__ cntf, int n) {
    int wave = threadIdx.x >> 6;
    int lane = threadIdx.x & 63;   // feature index
    int node0 = blockIdx.x * POOL_NPB;
    int nodeEnd = node0 + POOL_NPB;
    if (nodeEnd > n) nodeEnd = n;
    float bias = b3[lane];
    float acc = 0.0f, cnt = 0.0f;
    int curg = -1;
    for (int node = node0 + wave; node < nodeEnd; node += 4) {
        int g = batch[node];               // wave-uniform (lane = feature)
        if (g != curg) {                   // wave-uniform branch
            if (curg >= 0) {
                atomicAdd(&sums[curg * 64 + lane], acc);
                if (lane == 0) atomicAdd(&cntf[curg], cnt);
            }
            curg = g; acc = 0.0f; cnt = 0.0f;
        }
        acc += fmaxf(z3[node * 64 + lane] + bias, 0.0f);
        cnt += 1.0f;
    }
    if (curg >= 0) {
        atomicAdd(&sums[curg * 64 + lane], acc);
        if (lane == 0) atomicAdd(&cntf[curg], cnt);
    }
}

// per-graph: g = sums/max(cnt,1); hid = relu(g@Wl1+bl1); out = hid@Wl2+bl2
__global__ void mlp_kernel(const float* __restrict__ sums, const float* __restrict__ cntf,
                           const float* __restrict__ Wl1, const float* __restrict__ bl1,
                           const float* __restrict__ Wl2, const float* __restrict__ bl2,
                           float* __restrict__ out) {
    __shared__ float gv[64];
    __shared__ float hid[32];
    int g = blockIdx.x, t = threadIdx.x;
    float denom = fmaxf(cntf[g], 1.0f);
    gv[t] = sums[g * 64 + t] / denom;
    __syncthreads();
    if (t < 32) {
        float a = bl1[t];
#pragma unroll
        for (int k = 0; k < 64; ++k) a += gv[k] * Wl1[k * 32 + t];
        hid[t] = fmaxf(a, 0.0f);
    }
    __syncthreads();
    if (t == 0) {
        float o = bl2[0];
#pragma unroll
        for (int k = 0; k < 32; ++k) o += hid[k] * Wl2[k];
        out[g] = o;
    }
}

extern "C" void kernel_launch(void* const* d_in, const int* in_sizes, int n_in,
                              void* d_out, int out_size, void* d_ws, size_t ws_size,
                              hipStream_t stream) {
    const float* x   = (const float*)d_in[0];
    const int* ei    = (const int*)d_in[1];
    const int* batch = (const int*)d_in[2];
    const float* W1  = (const float*)d_in[3];
    const float* b1  = (const float*)d_in[4];
    const float* W2  = (const float*)d_in[5];
    const float* b2  = (const float*)d_in[6];
    const float* W3  = (const float*)d_in[7];
    const float* b3  = (const float*)d_in[8];
    const float* Wl1 = (const float*)d_in[9];
    const float* bl1 = (const float*)d_in[10];
    const float* Wl2 = (const float*)d_in[11];
    const float* bl2 = (const float*)d_in[12];
    float* out = (float*)d_out;

    const int N = N_NODES;
    const int E = in_sizes[1] / 2;   // 3.2M
    const int* src = ei;
    const int* dst = ei + E;

    char* ws = (char*)d_ws;
    int*   cnt     = (int*)(ws + OFF_CNT);
    int*   fill    = (int*)(ws + OFF_FILL);
    float* sums    = (float*)(ws + OFF_SUMS);
    float* cntf    = (float*)(ws + OFF_CNTF);
    int*   row_ptr = (int*)(ws + OFF_ROWPTR);
    float* dinv    = (float*)(ws + OFF_DINV);
    int*   blkSum  = (int*)(ws + OFF_BLKSUM);
    int*   blkOff  = (int*)(ws + OFF_BLKOFF);
    int*   col     = (int*)(ws + OFF_COL);
    float* xs1     = (float*)(ws + OFF_XS1);
    float* z1      = (float*)(ws + OFF_Z1);
    float* bufQ    = (float*)(ws + OFF_BUFQ);   // xs2, later z3
    float* bufR    = (float*)(ws + OFF_BUFR);   // z2, later ys
    float* bufP    = (float*)(ws + OFF_BUFP);   // h2

    // zero counters/accumulators
    {
        int nz = ZERO_BYTES / 4;
        zero_kernel<<<(nz + 255) / 256, 256, 0, stream>>>((int*)ws, nz);
    }

    // CSR build
    count_kernel<<<(E + 255) / 256, 256, 0, stream>>>(dst, cnt, E);
    int nb = (N + 1023) / 1024;   // 98
    scanA_kernel<<<nb, 1024, 0, stream>>>(cnt, row_ptr, blkSum, dinv, N);
    scanB_kernel<<<1, 128, 0, stream>>>(blkSum, blkOff, row_ptr, nb, N);
    scanC_kernel<<<nb, 1024, 0, stream>>>(row_ptr, blkOff, N);
    {
        int chunks = (E + SCAT_EPB - 1) / SCAT_EPB;
        scatter_kernel<<<chunks * 8, 256, 0, stream>>>(src, dst, row_ptr, fill, col, E);
    }

    // Layer 1: xs1 = dinv*x ; z1 = agg(xs1) ; xs2 = dinv*relu(z1@W1+b1)
    scale_x8_kernel<<<(N * 8 + 255) / 256, 256, 0, stream>>>(x, dinv, xs1, N * 8);
    agg_kernel<8><<<(N + 31) / 32, 256, 0, stream>>>(xs1, row_ptr, col, dinv, z1, N);
    gemm_kernel<8, 64, true, true, true><<<2560, 256, 0, stream>>>(z1, W1, b1, dinv, bufQ, N);

    // Layer 2: z2 = agg(xs2) ; h2 = relu(z2@W2+b2)
    agg_kernel<64><<<(N + 3) / 4, 256, 0, stream>>>(bufQ, row_ptr, col, dinv, bufR, N);
    gemm_kernel<64, 128, true, true, false><<<2560, 256, 0, stream>>>(bufR, W2, b2, nullptr, bufP, N);

    // Layer 3: ys = dinv*(h2@W3) ; z3 = agg(ys) ; (relu(z3+b3) fused into pool)
    gemm_kernel<128, 64, false, false, true><<<2560, 256, 0, stream>>>(bufP, W3, nullptr, dinv, bufR, N);
    agg_kernel<64><<<(N + 3) / 4, 256, 0, stream>>>(bufR, row_ptr, col, dinv, bufQ, N);

    // Pool + MLP head
    pool_kernel<<<(N + POOL_NPB - 1) / POOL_NPB, 256, 0, stream>>>(bufQ, b3, batch, sums, cntf, N);
    mlp_kernel<<<N_GRAPHS, 64, 0, stream>>>(sums, cntf, Wl1, bl1, Wl2, bl2, out);
}